// Round 11
// baseline (173.011 us; speedup 1.0000x reference)
//
#include <hip/hip_runtime.h>
#include <cstdint>

typedef unsigned short u16;
typedef short s16x8 __attribute__((ext_vector_type(8)));
typedef short s16x4 __attribute__((ext_vector_type(4)));
typedef float f32x4 __attribute__((ext_vector_type(4)));
typedef float f32x16 __attribute__((ext_vector_type(16)));

#define B_   4
#define T_   2048
#define C_   1024
#define H_   16
#define HD_  64
#define M_   8192      // B*T
#define N3_  3072      // 3*C

// 0.125 (1/sqrt(64)) * log2(e), folded into q at QKV-GEMM epilogue
#define QSCALE 0.18033688011112042f

// fp32 -> bf16 round-to-nearest-even
__device__ inline u16 f2b(float f) {
  union { float f; uint32_t u; } v; v.f = f;
  uint32_t u = v.u;
  return (u16)((u + 0x7FFFu + ((u >> 16) & 1u)) >> 16);
}

// pack 2 fp32 -> 2 bf16 in one dword (RNE): dst.lo = src0, dst.hi = src1
__device__ inline uint32_t cvtpk(float lo, float hi) {
  uint32_t r;
  asm("v_cvt_pk_bf16_f32 %0, %1, %2" : "=v"(r) : "v"(lo), "v"(hi));
  return r;
}

// async global->LDS, 16B per lane (dest = wave-uniform base + lane*16)
__device__ inline void gload_lds16(const void* g, void* l) {
  __builtin_amdgcn_global_load_lds(
      (const __attribute__((address_space(1))) void*)g,
      (__attribute__((address_space(3))) void*)l, 16, 0, 0);
}

// ---------------- convert x (fp32) -> bf16, same layout ----------------
__global__ __launch_bounds__(256) void cvt_f32_bf16(
    const float* __restrict__ in, u16* __restrict__ out, int n) {
  int i = (blockIdx.x * 256 + threadIdx.x) * 8;
  if (i >= n) return;
  float4 a = *(const float4*)(in + i);
  float4 b = *(const float4*)(in + i + 4);
  s16x8 r;
  r[0] = (short)f2b(a.x); r[1] = (short)f2b(a.y);
  r[2] = (short)f2b(a.z); r[3] = (short)f2b(a.w);
  r[4] = (short)f2b(b.x); r[5] = (short)f2b(b.y);
  r[6] = (short)f2b(b.z); r[7] = (short)f2b(b.w);
  *(s16x8*)(out + i) = r;
}

// ------- transpose+convert: W fp32 [K][N] -> WT bf16 [N][K] ------------
__global__ __launch_bounds__(256) void cvt_transpose(
    const float* __restrict__ W, u16* __restrict__ WT, int K, int N) {
  __shared__ u16 tile[64][65];
  int n0 = blockIdx.x * 64, k0 = blockIdx.y * 64;
  int j = threadIdx.x & 63, i0 = threadIdx.x >> 6;  // j fast, i0 in 0..3
#pragma unroll
  for (int i = i0; i < 64; i += 4)
    tile[i][j] = f2b(W[(size_t)(k0 + i) * N + n0 + j]);
  __syncthreads();
#pragma unroll
  for (int i = i0; i < 64; i += 4)
    WT[(size_t)(n0 + i) * K + k0 + j] = tile[j][i];
}

// ========== 8-phase 256x256 pipelined GEMM (m201-style schedule) =======
// BK=64, 512 threads = 8 waves (2M x 4N), per-wave 128x64.
// LDS 128KB = 2buf x 2half x {A,B} x 128rows x 64k bf16. Each phase stages
// EXACTLY ONE 16KB half-tile (2 gloads/thread) into a slot whose last
// reader finished >=1 barrier earlier; counted vmcnt(4) only at phases
// 4/8 waits on loads issued 4-6 phases before (never a full drain).
// Chunk-XOR swizzle via pre-swizzled global source (0 conflicts).
// MODE 0: fp32 out.  MODE 1: scatter bf16 q,k->[B,H,T,64] (q pre-scaled),
//                            v -> transposed [B,H,64,T].
template <int MODE>
__global__ __launch_bounds__(512, 2) void gemm8p(
    const u16* __restrict__ A, const u16* __restrict__ Bt,
    const float* __restrict__ bias, float* __restrict__ outf,
    u16* __restrict__ qo, u16* __restrict__ ko, u16* __restrict__ vo,
    int M, int N, int K) {
  __shared__ u16 As[2][2][128 * 64];   // [buf][half] 16KB units, 64KB
  __shared__ u16 Bs[2][2][128 * 64];   //                          64KB

  int nwg = gridDim.x;
  int bid0 = blockIdx.x;
  int bid = (bid0 & 7) * (nwg >> 3) + (bid0 >> 3);   // XCD swizzle (nwg%8==0)
  int nbn = N >> 8;
  int bm = bid / nbn, bn = bid % nbn;
  int m0 = bm * 256, n0 = bn * 256;
  int tid = threadIdx.x, lane = tid & 63, w = tid >> 6;
  int l15 = lane & 15, g = lane >> 4;
  int Ah = w >> 2;            // wave's A row-half (0/1)
  int Bh = (w & 3) >> 1;      // wave's B row-half
  int bno = (w & 1) * 64;     // n-offset inside B half
  int nt = K >> 6;            // K-tiles (even: K=1024 -> 16)
  int ck0 = (g ^ (l15 & 7)) * 8;          // swizzled read chunks
  int ck1 = ((4 + g) ^ (l15 & 7)) * 8;

  f32x4 acc[8][4] = {};
  s16x8 af[4][2], bf0[2][2], bf1[2][2];

#define BAR() asm volatile("s_barrier" ::: "memory")
#define WAITL0() do { asm volatile("s_waitcnt lgkmcnt(0)" ::: "memory"); \
  __builtin_amdgcn_sched_barrier(0); } while (0)
#define STAGE_A8(bb, uh, kt) do { \
  _Pragma("unroll") for (int ld = 0; ld < 2; ++ld) { \
    int slot = ld * 512 + tid, row = slot >> 3, pc = slot & 7; \
    int sc = (pc ^ (row & 7)) * 8; \
    gload_lds16(A + (size_t)(m0 + (uh) * 128 + row) * K + (kt) * 64 + sc, \
                &As[bb][uh][slot * 8]); \
  } } while (0)
#define STAGE_B8(bb, uh, kt) do { \
  _Pragma("unroll") for (int ld = 0; ld < 2; ++ld) { \
    int slot = ld * 512 + tid, row = slot >> 3, pc = slot & 7; \
    int sc = (pc ^ (row & 7)) * 8; \
    gload_lds16(Bt + (size_t)(n0 + (uh) * 128 + row) * K + (kt) * 64 + sc, \
                &Bs[bb][uh][slot * 8]); \
  } } while (0)
#define LDA8(bb, mq) do { \
  _Pragma("unroll") for (int mi = 0; mi < 4; ++mi) { \
    int rw = ((mq) * 64 + mi * 16 + l15) * 64; \
    af[mi][0] = *(const s16x8*)&As[bb][Ah][rw + ck0]; \
    af[mi][1] = *(const s16x8*)&As[bb][Ah][rw + ck1]; \
  } } while (0)
#define LDB8(bb, nq, bfr) do { \
  _Pragma("unroll") for (int ni = 0; ni < 2; ++ni) { \
    int rw = (bno + (nq) * 32 + ni * 16 + l15) * 64; \
    bfr[ni][0] = *(const s16x8*)&Bs[bb][Bh][rw + ck0]; \
    bfr[ni][1] = *(const s16x8*)&Bs[bb][Bh][rw + ck1]; \
  } } while (0)
#define QUAD8(mq, nq, bfr) do { \
  __builtin_amdgcn_s_setprio(1); \
  _Pragma("unroll") for (int mi = 0; mi < 4; ++mi) \
  _Pragma("unroll") for (int ni = 0; ni < 2; ++ni) \
  _Pragma("unroll") for (int ks = 0; ks < 2; ++ks) \
    acc[(mq) * 4 + mi][(nq) * 2 + ni] = \
        __builtin_amdgcn_mfma_f32_16x16x32_bf16( \
            af[mi][ks], bfr[ni][ks], acc[(mq) * 4 + mi][(nq) * 2 + ni], \
            0, 0, 0); \
  __builtin_amdgcn_s_setprio(0); \
} while (0)

  // prologue: tile0 fully (buf0) + tile1 B-halves (buf1); wait tile0 only
  STAGE_B8(0, 0, 0); STAGE_B8(0, 1, 0);
  STAGE_A8(0, 0, 0); STAGE_A8(0, 1, 0);
  STAGE_B8(1, 0, 1); STAGE_B8(1, 1, 1);
  asm volatile("s_waitcnt vmcnt(4)" ::: "memory");
  BAR();

  for (int t = 0; t < nt; t += 2) {
    int t1 = t + 1;
    int t2 = (t + 2 < nt) ? t + 2 : 0;   // wrap: harmless dummy stages
    int t3 = (t + 3 < nt) ? t + 3 : 1;
    // ---- K-tile t (buf0) ----
    // P1: quad(m0,n0); reads A-mq0 + B-nq0; stage A0(t+1)->buf1
    LDA8(0, 0); LDB8(0, 0, bf0);
    STAGE_A8(1, 0, t1);
    asm volatile("s_waitcnt lgkmcnt(8)" ::: "memory");
    BAR(); WAITL0();
    QUAD8(0, 0, bf0); BAR();
    // P2: quad(m0,n1); reads B-nq1; stage A1(t+1)->buf1
    LDB8(0, 1, bf1);
    STAGE_A8(1, 1, t1);
    BAR(); WAITL0();
    QUAD8(0, 1, bf1); BAR();
    // P3: quad(m1,n1); reads A-mq1; stage B0(t+2)->buf0 (B reads done P2)
    LDA8(0, 1);
    STAGE_B8(0, 0, t2);
    BAR(); WAITL0();
    QUAD8(1, 1, bf1); BAR();
    // P4: quad(m1,n0); no reads; stage B1(t+2)->buf0; counted vmcnt
    STAGE_B8(0, 1, t2);
    asm volatile("s_waitcnt vmcnt(4)" ::: "memory");
    BAR();
    QUAD8(1, 0, bf0); BAR();
    // ---- K-tile t+1 (buf1) ----
    // P5: stage A0(t+2)->buf0 (A reads of buf0 done P3)
    LDA8(1, 0); LDB8(1, 0, bf0);
    STAGE_A8(0, 0, t2);
    asm volatile("s_waitcnt lgkmcnt(8)" ::: "memory");
    BAR(); WAITL0();
    QUAD8(0, 0, bf0); BAR();
    // P6: stage A1(t+2)->buf0
    LDB8(1, 1, bf1);
    STAGE_A8(0, 1, t2);
    BAR(); WAITL0();
    QUAD8(0, 1, bf1); BAR();
    // P7: stage B0(t+3)->buf1 (buf1 B reads done P6)
    LDA8(1, 1);
    STAGE_B8(1, 0, t3);
    BAR(); WAITL0();
    QUAD8(1, 1, bf1); BAR();
    // P8: stage B1(t+3)->buf1; counted vmcnt
    STAGE_B8(1, 1, t3);
    asm volatile("s_waitcnt vmcnt(4)" ::: "memory");
    BAR();
    QUAD8(1, 0, bf0); BAR();
  }
#undef BAR
#undef WAITL0
#undef STAGE_A8
#undef STAGE_B8
#undef LDA8
#undef LDB8
#undef QUAD8

  // ---- epilogue
  int which = (MODE == 1) ? (n0 >> 10) : 0;   // 256 divides 1024: uniform
#pragma unroll
  for (int mf = 0; mf < 8; ++mf)
#pragma unroll
    for (int na = 0; na < 4; ++na) {
      int col = n0 + (w & 3) * 64 + na * 16 + l15;
      float bv = bias[col];
      int row0 = m0 + (w >> 2) * 128 + mf * 16 + g * 4;
      if (MODE == 0) {
#pragma unroll
        for (int r = 0; r < 4; ++r)
          outf[(size_t)(row0 + r) * N + col] = acc[mf][na][r] + bv;
      } else {
        int hc = col & 1023;
        int h = hc >> 6, d = hc & 63;
        int b = row0 >> 11, t0 = row0 & 2047;
        if (which == 2) {
          s16x4 pv;
#pragma unroll
          for (int r = 0; r < 4; ++r) pv[r] = (short)f2b(acc[mf][na][r] + bv);
          *(s16x4*)(vo + ((size_t)((b * 16 + h) * 64 + d)) * 2048 + t0) = pv;
        } else {
          u16* dst = (which == 0) ? qo : ko;
          float sc2 = (which == 0) ? QSCALE : 1.0f;
#pragma unroll
          for (int r = 0; r < 4; ++r)
            dst[(((size_t)(b * 16 + h)) * 2048 + (t0 + r)) * 64 + d] =
                f2b((acc[mf][na][r] + bv) * sc2);
        }
      }
    }
}

// ---------------- GEMM: C[M][N] = A[M][K] * Bt[N][K]^T + bias ----------
// 2-barrier structure, BK=64, 128x128 tile, 4 waves, 32 KB LDS (for proj:
// grid 512 = 2 blocks/CU; the 256^2 8-phase would leave half the GPU idle).
template <int MODE>
__global__ __launch_bounds__(256, 4) void gemm_bt(
    const u16* __restrict__ A, const u16* __restrict__ Bt,
    const float* __restrict__ bias, float* __restrict__ outf,
    u16* __restrict__ qo, u16* __restrict__ ko, u16* __restrict__ vo,
    int M, int N, int K) {
  __shared__ u16 As[128 * 64];   // 16 KB, rows 128B, chunk-swizzled
  __shared__ u16 Bs[128 * 64];   // 16 KB

  int nwg = gridDim.x;
  int bid0 = blockIdx.x;
  int bid = (bid0 & 7) * (nwg >> 3) + (bid0 >> 3);   // XCD swizzle (nwg%8==0)
  int nbn = N >> 7;
  int bm = bid / nbn, bn = bid % nbn;
  int m0 = bm * 128, n0 = bn * 128;
  int tid = threadIdx.x;
  int lane = tid & 63, w = tid >> 6;
  int wm = (w >> 1) * 64, wn = (w & 1) * 64;
  int l15 = lane & 15, g = lane >> 4;

  f32x4 acc[4][4] = {};

  for (int kb = 0; kb < K; kb += 64) {
    __syncthreads();  // all waves done reading previous tile
#pragma unroll
    for (int p = 0; p < 4; ++p) {
      int idx = p * 256 + tid;
      int row = idx >> 3, pc = idx & 7;
      int sc = (pc ^ (row & 7)) * 8;     // pre-swizzled source chunk
      gload_lds16(A  + (size_t)(m0 + row) * K + kb + sc, &As[idx * 8]);
      gload_lds16(Bt + (size_t)(n0 + row) * K + kb + sc, &Bs[idx * 8]);
    }
    __syncthreads();  // (compiler emits vmcnt(0) before barrier)

#pragma unroll
    for (int ks = 0; ks < 2; ++ks) {
      int ck = ((g + 4 * ks) ^ (l15 & 7)) * 8;   // swizzled read chunk
      s16x8 af[4], bf[4];
#pragma unroll
      for (int mi = 0; mi < 4; ++mi)
        af[mi] = *(const s16x8*)&As[(wm + mi * 16 + l15) * 64 + ck];
#pragma unroll
      for (int ni = 0; ni < 4; ++ni)
        bf[ni] = *(const s16x8*)&Bs[(wn + ni * 16 + l15) * 64 + ck];
#pragma unroll
      for (int mi = 0; mi < 4; ++mi)
#pragma unroll
        for (int ni = 0; ni < 4; ++ni)
          acc[mi][ni] = __builtin_amdgcn_mfma_f32_16x16x32_bf16(
              af[mi], bf[ni], acc[mi][ni], 0, 0, 0);
    }
  }

#pragma unroll
  for (int mi = 0; mi < 4; ++mi)
#pragma unroll
    for (int ni = 0; ni < 4; ++ni) {
      int col = n0 + wn + ni * 16 + l15;
      float bv = bias[col];
      int row0 = m0 + wm + mi * 16 + g * 4;  // C/D: col=lane&15, row=(lane>>4)*4+reg
      if (MODE == 0) {
#pragma unroll
        for (int r = 0; r < 4; ++r)
          outf[(size_t)(row0 + r) * N + col] = acc[mi][ni][r] + bv;
      } else {
        int which = col >> 10, hc = col & 1023;
        int h = hc >> 6, d = hc & 63;
        int b = row0 >> 11, t0 = row0 & 2047;
        if (which == 2) {
          s16x4 pv;
#pragma unroll
          for (int r = 0; r < 4; ++r) pv[r] = (short)f2b(acc[mi][ni][r] + bv);
          *(s16x4*)(vo + ((size_t)((b * 16 + h) * 64 + d)) * 2048 + t0) = pv;
        } else {
          u16* dst = (which == 0) ? qo : ko;
          float sc2 = (which == 0) ? QSCALE : 1.0f;
#pragma unroll
          for (int r = 0; r < 4; ++r)
            dst[(((size_t)(b * 16 + h)) * 2048 + (t0 + r)) * 64 + d] =
                f2b((acc[mi][ni][r] + bv) * sc2);
        }
      }
    }
}

// ---------------- flash attention, causal, 32x32 MFMA, swapped QK^T ----
// (unchanged from round 10 — passed, ~55-60 us)
__global__ __launch_bounds__(256, 3) void attn_fwd(
    const u16* __restrict__ Q, const u16* __restrict__ Kg,
    const u16* __restrict__ Vt, u16* __restrict__ Y) {
  __shared__ u16 Ks[64 * 64];   // K tile  [kv][hd], 128B rows, swizzled
  __shared__ u16 Vs[64 * 64];   // V^T tile [hd][kv], 128B rows, swizzled

  int bid = blockIdx.x;
  int bh = bid & 63;
  int qb = 15 - (bid >> 6);       // big tiles first
  int tid = threadIdx.x, lane = tid & 63, w = tid >> 6;
  int l31 = lane & 31, half = lane >> 5;

  const u16* Qh = Q  + (size_t)bh * T_ * HD_;
  const u16* Kh = Kg + (size_t)bh * T_ * HD_;
  const u16* Vh = Vt + (size_t)bh * HD_ * T_;   // [64][2048]

  int q0 = qb * 128;
  int qw = q0 + w * 32;           // wave's first q row
  int qrow = qw + l31;            // THIS lane's q row

  s16x8 qa[4];
#pragma unroll
  for (int kst = 0; kst < 4; ++kst)
    qa[kst] = *(const s16x8*)(Qh + (size_t)qrow * HD_ + kst * 16 + half * 8);

  f32x16 oacc[2] = {};            // O^T: [hb] -> hd = hb*32+(r&3)+8(r>>2)+4*half
  float m = -3.0e30f, l = 0.f;

  int sr = tid >> 3, sc = tid & 7;
  int wswz = (sr & 7) << 4;
  int rswz = (l31 & 7) << 4;
  char* KsB = (char*)Ks;
  char* VsB = (char*)Vs;

  s16x8 kr0 = *(const s16x8*)(Kh + (size_t)sr * HD_ + sc * 8);
  s16x8 kr1 = *(const s16x8*)(Kh + (size_t)(sr + 32) * HD_ + sc * 8);
  s16x8 vr0 = *(const s16x8*)(Vh + (size_t)sr * T_ + sc * 8);
  s16x8 vr1 = *(const s16x8*)(Vh + (size_t)(sr + 32) * T_ + sc * 8);

  int ntile = 2 * qb + 2;
  for (int kt = 0; kt < ntile; ++kt) {
    int kvb = kt * 64;
    __syncthreads();
    *(s16x8*)(KsB + sr * 128 + ((sc * 16) ^ wswz))        = kr0;
    *(s16x8*)(KsB + (sr + 32) * 128 + ((sc * 16) ^ wswz)) = kr1;
    *(s16x8*)(VsB + sr * 128 + ((sc * 16) ^ wswz))        = vr0;
    *(s16x8*)(VsB + (sr + 32) * 128 + ((sc * 16) ^ wswz)) = vr1;
    __syncthreads();

    {
      int kvn = (kt + 1 < ntile) ? (kt + 1) * 64 : 0;
      kr0 = *(const s16x8*)(Kh + (size_t)(kvn + sr) * HD_ + sc * 8);
      kr1 = *(const s16x8*)(Kh + (size_t)(kvn + sr + 32) * HD_ + sc * 8);
      vr0 = *(const s16x8*)(Vh + (size_t)sr * T_ + kvn + sc * 8);
      vr1 = *(const s16x8*)(Vh + (size_t)(sr + 32) * T_ + kvn + sc * 8);
    }

    if (kvb > qw + 31) continue;

    f32x16 s0 = {}, s1 = {};
    __builtin_amdgcn_s_setprio(1);
#pragma unroll
    for (int kst = 0; kst < 4; ++kst) {
      s16x8 kb0 = *(const s16x8*)(KsB +
          (((l31) * 128 + kst * 32 + half * 16) ^ rswz));
      s0 = __builtin_amdgcn_mfma_f32_32x32x16_bf16(kb0, qa[kst], s0, 0, 0, 0);
      s16x8 kb1 = *(const s16x8*)(KsB +
          (((32 + l31) * 128 + kst * 32 + half * 16) ^ rswz));
      s1 = __builtin_amdgcn_mfma_f32_32x32x16_bf16(kb1, qa[kst], s1, 0, 0, 0);
    }
    __builtin_amdgcn_s_setprio(0);

    if (kvb + 63 > qw) {
#pragma unroll
      for (int r = 0; r < 16; ++r) {
        int kv0 = kvb + (r & 3) + 8 * (r >> 2) + 4 * half;
        if (kv0 > qrow) s0[r] = -1e30f;
        if (kv0 + 32 > qrow) s1[r] = -1e30f;
      }
    }

    float a0 = fmaxf(fmaxf(s0[0], s0[1]), fmaxf(s0[2], s0[3]));
    float a1 = fmaxf(fmaxf(s0[4], s0[5]), fmaxf(s0[6], s0[7]));
    float a2 = fmaxf(fmaxf(s0[8], s0[9]), fmaxf(s0[10], s0[11]));
    float a3 = fmaxf(fmaxf(s0[12], s0[13]), fmaxf(s0[14], s0[15]));
    float a4 = fmaxf(fmaxf(s1[0], s1[1]), fmaxf(s1[2], s1[3]));
    float a5 = fmaxf(fmaxf(s1[4], s1[5]), fmaxf(s1[6], s1[7]));
    float a6 = fmaxf(fmaxf(s1[8], s1[9]), fmaxf(s1[10], s1[11]));
    float a7 = fmaxf(fmaxf(s1[12], s1[13]), fmaxf(s1[14], s1[15]));
    float mx = fmaxf(fmaxf(fmaxf(a0, a1), fmaxf(a2, a3)),
                     fmaxf(fmaxf(a4, a5), fmaxf(a6, a7)));
    mx = fmaxf(mx, __shfl_xor(mx, 32, 64));

    if (!__all(mx <= m + 8.0f)) {
      float mn = fmaxf(m, mx);
      float alpha = __builtin_amdgcn_exp2f(m - mn);
      m = mn;
      l *= alpha;
#pragma unroll
      for (int i = 0; i < 16; ++i) { oacc[0][i] *= alpha; oacc[1][i] *= alpha; }
    }

    float rs = 0.f;
#pragma unroll
    for (int r = 0; r < 16; ++r) {
      float p0 = __builtin_amdgcn_exp2f(s0[r] - m);
      float p1 = __builtin_amdgcn_exp2f(s1[r] - m);
      s0[r] = p0; s1[r] = p1;
      rs += p0 + p1;
    }
    rs += __shfl_xor(rs, 32, 64);
    l += rs;

    s16x8 pb[4];
#pragma unroll
    for (int ks4 = 0; ks4 < 4; ++ks4) {
      const f32x16& sv = (ks4 < 2) ? s0 : s1;
      const int R = (ks4 & 1) * 8;
      uint32_t A0 = cvtpk(sv[R + 0], sv[R + 1]);
      uint32_t A1 = cvtpk(sv[R + 2], sv[R + 3]);
      uint32_t B0 = cvtpk(sv[R + 4], sv[R + 5]);
      uint32_t B1 = cvtpk(sv[R + 6], sv[R + 7]);
      uint32_t r0 = (uint32_t)__shfl_xor((int)(half ? A0 : B0), 32, 64);
      uint32_t r1 = (uint32_t)__shfl_xor((int)(half ? A1 : B1), 32, 64);
      union { uint32_t u[4]; s16x8 v; } pk_;
      pk_.u[0] = half ? r0 : A0;
      pk_.u[1] = half ? r1 : A1;
      pk_.u[2] = half ? B0 : r0;
      pk_.u[3] = half ? B1 : r1;
      pb[ks4] = pk_.v;
    }

    __builtin_amdgcn_s_setprio(1);
#pragma unroll
    for (int hb = 0; hb < 2; ++hb)
#pragma unroll
      for (int ks4 = 0; ks4 < 4; ++ks4) {
        s16x8 va = *(const s16x8*)(VsB +
            (((hb * 32 + l31) * 128 + ks4 * 32 + half * 16) ^ rswz));
        oacc[hb] = __builtin_amdgcn_mfma_f32_32x32x16_bf16(va, pb[ks4],
                                                           oacc[hb], 0, 0, 0);
      }
    __builtin_amdgcn_s_setprio(0);
  }

  int b = bh >> 4, h = bh & 15;
  float inv = 1.0f / l;
  u16* yrow = Y + ((size_t)b * T_ + qrow) * C_ + h * 64;
#pragma unroll
  for (int hb = 0; hb < 2; ++hb)
#pragma unroll
    for (int rg = 0; rg < 4; ++rg) {
      union { uint32_t u[2]; s16x4 v; } o;
      o.u[0] = cvtpk(oacc[hb][rg * 4 + 0] * inv, oacc[hb][rg * 4 + 1] * inv);
      o.u[1] = cvtpk(oacc[hb][rg * 4 + 2] * inv, oacc[hb][rg * 4 + 3] * inv);
      *(s16x4*)(yrow + hb * 32 + rg * 8 + half * 4) = o.v;
    }
}

// ----------------------------- launcher --------------------------------
extern "C" void kernel_launch(void* const* d_in, const int* in_sizes, int n_in,
                              void* d_out, int out_size, void* d_ws, size_t ws_size,
                              hipStream_t stream) {
  const float* x      = (const float*)d_in[0];
  const float* w_attn = (const float*)d_in[1];
  const float* b_attn = (const float*)d_in[2];
  const float* w_proj = (const float*)d_in[3];
  const float* b_proj = (const float*)d_in[4];
  float* out = (float*)d_out;

  u16* ws  = (u16*)d_ws;
  u16* xb  = ws;                           // [8192][1024] bf16 (reused as ya)
  u16* wat = xb  + (size_t)M_ * C_;        // [3072][1024] bf16 (W_attn^T)
  u16* wpt = wat + (size_t)N3_ * C_;       // [1024][1024] bf16 (W_proj^T)
  u16* q   = wpt + (size_t)C_ * C_;        // [B,H,T,64] bf16 (pre-scaled)
  u16* k   = q   + (size_t)M_ * C_;        // [B,H,T,64] bf16
  u16* v   = k   + (size_t)M_ * C_;        // [B,H,64,T] bf16 (TRANSPOSED)
  u16* ya  = xb;                           // reuse: xb dead after QKV GEMM

  cvt_f32_bf16<<<dim3((M_ * C_) / (256 * 8)), dim3(256), 0, stream>>>(x, xb, M_ * C_);
  cvt_transpose<<<dim3(N3_ / 64, C_ / 64), dim3(256), 0, stream>>>(w_attn, wat, C_, N3_);
  cvt_transpose<<<dim3(C_ / 64, C_ / 64), dim3(256), 0, stream>>>(w_proj, wpt, C_, C_);

  gemm8p<1><<<dim3((M_ / 256) * (N3_ / 256)), dim3(512), 0, stream>>>(
      xb, wat, b_attn, nullptr, q, k, v, M_, N3_, C_);

  attn_fwd<<<dim3(64 * 16), dim3(256), 0, stream>>>(q, k, v, ya);

  gemm_bt<0><<<dim3((M_ / 128) * (C_ / 128)), dim3(256), 0, stream>>>(
      ya, wpt, b_proj, out, nullptr, nullptr, nullptr, M_, C_, C_);
}

// Round 12
// 165.625 us; speedup vs baseline: 1.0446x; 1.0446x over previous
//
#include <hip/hip_runtime.h>
#include <cstdint>

typedef unsigned short u16;
typedef short s16x8 __attribute__((ext_vector_type(8)));
typedef short s16x4 __attribute__((ext_vector_type(4)));
typedef float f32x4 __attribute__((ext_vector_type(4)));
typedef float f32x16 __attribute__((ext_vector_type(16)));

#define B_   4
#define T_   2048
#define C_   1024
#define H_   16
#define HD_  64
#define M_   8192      // B*T
#define N3_  3072      // 3*C

// 0.125 (1/sqrt(64)) * log2(e), folded into q at QKV-GEMM epilogue
#define QSCALE 0.18033688011112042f

// fp32 -> bf16 round-to-nearest-even
__device__ inline u16 f2b(float f) {
  union { float f; uint32_t u; } v; v.f = f;
  uint32_t u = v.u;
  return (u16)((u + 0x7FFFu + ((u >> 16) & 1u)) >> 16);
}

// pack 2 fp32 -> 2 bf16 in one dword (RNE): dst.lo = src0, dst.hi = src1
__device__ inline uint32_t cvtpk(float lo, float hi) {
  uint32_t r;
  asm("v_cvt_pk_bf16_f32 %0, %1, %2" : "=v"(r) : "v"(lo), "v"(hi));
  return r;
}

// async global->LDS, 16B per lane (dest = wave-uniform base + lane*16)
__device__ inline void gload_lds16(const void* g, void* l) {
  __builtin_amdgcn_global_load_lds(
      (const __attribute__((address_space(1))) void*)g,
      (__attribute__((address_space(3))) void*)l, 16, 0, 0);
}

// ------- transpose+convert: W fp32 [K][N] -> WT bf16 [N][K] ------------
__global__ __launch_bounds__(256) void cvt_transpose(
    const float* __restrict__ W, u16* __restrict__ WT, int K, int N) {
  __shared__ u16 tile[64][65];
  int n0 = blockIdx.x * 64, k0 = blockIdx.y * 64;
  int j = threadIdx.x & 63, i0 = threadIdx.x >> 6;  // j fast, i0 in 0..3
#pragma unroll
  for (int i = i0; i < 64; i += 4)
    tile[i][j] = f2b(W[(size_t)(k0 + i) * N + n0 + j]);
  __syncthreads();
#pragma unroll
  for (int i = i0; i < 64; i += 4)
    WT[(size_t)(n0 + i) * K + k0 + j] = tile[j][i];
}

// ---------------- GEMM: C[M][N] = A[M][K] * Bt[N][K]^T + bias ----------
// 2-barrier structure (measured-best), BK=64, 128x128 tile, 4 waves,
// 32 KB LDS. Chunk-XOR swizzle -> 0 conflicts.
// AF32=1: A is fp32, staged via regs (coalesced float4 loads prefetched
// one tile ahead + cvt_pk + swizzled ds_write_b64) — fuses the x->bf16
// conversion into the GEMM. AF32=0: A is bf16, staged via gload_lds.
// MODE 0: fp32 out.  MODE 1: scatter bf16 q,k->[B,H,T,64] (q pre-scaled),
//                            v -> transposed [B,H,64,T].
template <int MODE, int AF32>
__global__ __launch_bounds__(256, 4) void gemm_bt(
    const void* __restrict__ Araw, const u16* __restrict__ Bt,
    const float* __restrict__ bias, float* __restrict__ outf,
    u16* __restrict__ qo, u16* __restrict__ ko, u16* __restrict__ vo,
    int M, int N, int K) {
  __shared__ u16 As[128 * 64];   // 16 KB, rows 128B, chunk-swizzled
  __shared__ u16 Bs[128 * 64];   // 16 KB
  const u16*   A16 = (const u16*)Araw;
  const float* A32 = (const float*)Araw;

  int nwg = gridDim.x;
  int bid0 = blockIdx.x;
  int bid = (bid0 & 7) * (nwg >> 3) + (bid0 >> 3);   // XCD swizzle (nwg%8==0)
  int nbn = N >> 7;
  int bm = bid / nbn, bn = bid % nbn;
  int m0 = bm * 128, n0 = bn * 128;
  int tid = threadIdx.x;
  int lane = tid & 63, w = tid >> 6;
  int wm = (w >> 1) * 64, wn = (w & 1) * 64;
  int l15 = lane & 15, g = lane >> 4;

  f32x4 acc[4][4] = {};

  // --- AF32 A-staging geometry: pass p covers rows p*16+tr, 16 lanes/row
  int tr = tid >> 4;                 // 0..15
  int tc = tid & 15;                 // 16B chunk-of-row (4 fp32)
  const float* Afp = AF32 ? (A32 + (size_t)(m0 + tr) * K + tc * 4) : nullptr;
  // dest u16 offset base: slot constant across p (16 = 0 mod 8)
  int aslot = ((tc >> 1) ^ (tr & 7)) * 8 + (tid & 1) * 4;
  f32x4 fa[8];
  if (AF32) {
#pragma unroll
    for (int p = 0; p < 8; ++p)
      fa[p] = *(const f32x4*)(Afp + (size_t)p * 16 * K);
  }

  for (int kb = 0; kb < K; kb += 64) {
    __syncthreads();  // all waves done reading previous tile
    if (AF32) {
#pragma unroll
      for (int p = 0; p < 8; ++p) {
        uint32_t d0 = cvtpk(fa[p][0], fa[p][1]);
        uint32_t d1 = cvtpk(fa[p][2], fa[p][3]);
        uint2 dw; dw.x = d0; dw.y = d1;
        *(uint2*)&As[(p * 16 + tr) * 64 + aslot] = dw;
      }
#pragma unroll
      for (int p = 0; p < 4; ++p) {
        int idx = p * 256 + tid;
        int row = idx >> 3, pc = idx & 7;
        int sc = (pc ^ (row & 7)) * 8;
        gload_lds16(Bt + (size_t)(n0 + row) * K + kb + sc, &Bs[idx * 8]);
      }
    } else {
#pragma unroll
      for (int p = 0; p < 4; ++p) {
        int idx = p * 256 + tid;
        int row = idx >> 3, pc = idx & 7;
        int sc = (pc ^ (row & 7)) * 8;     // pre-swizzled source chunk
        gload_lds16(A16 + (size_t)(m0 + row) * K + kb + sc, &As[idx * 8]);
        gload_lds16(Bt  + (size_t)(n0 + row) * K + kb + sc, &Bs[idx * 8]);
      }
    }
    __syncthreads();  // (vmcnt(0)+lgkmcnt(0) drained by compiler)

    if (AF32) {       // T14: prefetch next tile's fp32 A into regs now
      int kn = (kb + 64 < K) ? kb + 64 : 0;
#pragma unroll
      for (int p = 0; p < 8; ++p)
        fa[p] = *(const f32x4*)(Afp + (size_t)p * 16 * K + kn);
    }

#pragma unroll
    for (int ks = 0; ks < 2; ++ks) {
      int ck = ((g + 4 * ks) ^ (l15 & 7)) * 8;   // swizzled read chunk
      s16x8 af[4], bf[4];
#pragma unroll
      for (int mi = 0; mi < 4; ++mi)
        af[mi] = *(const s16x8*)&As[(wm + mi * 16 + l15) * 64 + ck];
#pragma unroll
      for (int ni = 0; ni < 4; ++ni)
        bf[ni] = *(const s16x8*)&Bs[(wn + ni * 16 + l15) * 64 + ck];
#pragma unroll
      for (int mi = 0; mi < 4; ++mi)
#pragma unroll
        for (int ni = 0; ni < 4; ++ni)
          acc[mi][ni] = __builtin_amdgcn_mfma_f32_16x16x32_bf16(
              af[mi], bf[ni], acc[mi][ni], 0, 0, 0);
    }
  }

#pragma unroll
  for (int mi = 0; mi < 4; ++mi)
#pragma unroll
    for (int ni = 0; ni < 4; ++ni) {
      int col = n0 + wn + ni * 16 + l15;
      float bv = bias[col];
      int row0 = m0 + wm + mi * 16 + g * 4;  // C/D: col=lane&15, row=(lane>>4)*4+reg
      if (MODE == 0) {
#pragma unroll
        for (int r = 0; r < 4; ++r)
          outf[(size_t)(row0 + r) * N + col] = acc[mi][ni][r] + bv;
      } else {
        int which = col >> 10, hc = col & 1023;
        int h = hc >> 6, d = hc & 63;
        int b = row0 >> 11, t0 = row0 & 2047;
        if (which == 2) {
          s16x4 pv;
#pragma unroll
          for (int r = 0; r < 4; ++r) pv[r] = (short)f2b(acc[mi][ni][r] + bv);
          *(s16x4*)(vo + ((size_t)((b * 16 + h) * 64 + d)) * 2048 + t0) = pv;
        } else {
          u16* dst = (which == 0) ? qo : ko;
          float sc2 = (which == 0) ? QSCALE : 1.0f;
#pragma unroll
          for (int r = 0; r < 4; ++r)
            dst[(((size_t)(b * 16 + h)) * 2048 + (t0 + r)) * 64 + d] =
                f2b((acc[mi][ni][r] + bv) * sc2);
        }
      }
    }
}

// ---------------- flash attention, causal, 32x32 MFMA, swapped QK^T ----
// (unchanged from round 10 — passed)
__global__ __launch_bounds__(256, 3) void attn_fwd(
    const u16* __restrict__ Q, const u16* __restrict__ Kg,
    const u16* __restrict__ Vt, u16* __restrict__ Y) {
  __shared__ u16 Ks[64 * 64];   // K tile  [kv][hd], 128B rows, swizzled
  __shared__ u16 Vs[64 * 64];   // V^T tile [hd][kv], 128B rows, swizzled

  int bid = blockIdx.x;
  int bh = bid & 63;
  int qb = 15 - (bid >> 6);       // big tiles first
  int tid = threadIdx.x, lane = tid & 63, w = tid >> 6;
  int l31 = lane & 31, half = lane >> 5;

  const u16* Qh = Q  + (size_t)bh * T_ * HD_;
  const u16* Kh = Kg + (size_t)bh * T_ * HD_;
  const u16* Vh = Vt + (size_t)bh * HD_ * T_;   // [64][2048]

  int q0 = qb * 128;
  int qw = q0 + w * 32;           // wave's first q row
  int qrow = qw + l31;            // THIS lane's q row

  s16x8 qa[4];
#pragma unroll
  for (int kst = 0; kst < 4; ++kst)
    qa[kst] = *(const s16x8*)(Qh + (size_t)qrow * HD_ + kst * 16 + half * 8);

  f32x16 oacc[2] = {};            // O^T: [hb] -> hd = hb*32+(r&3)+8(r>>2)+4*half
  float m = -3.0e30f, l = 0.f;

  int sr = tid >> 3, sc = tid & 7;
  int wswz = (sr & 7) << 4;
  int rswz = (l31 & 7) << 4;
  char* KsB = (char*)Ks;
  char* VsB = (char*)Vs;

  s16x8 kr0 = *(const s16x8*)(Kh + (size_t)sr * HD_ + sc * 8);
  s16x8 kr1 = *(const s16x8*)(Kh + (size_t)(sr + 32) * HD_ + sc * 8);
  s16x8 vr0 = *(const s16x8*)(Vh + (size_t)sr * T_ + sc * 8);
  s16x8 vr1 = *(const s16x8*)(Vh + (size_t)(sr + 32) * T_ + sc * 8);

  int ntile = 2 * qb + 2;
  for (int kt = 0; kt < ntile; ++kt) {
    int kvb = kt * 64;
    __syncthreads();
    *(s16x8*)(KsB + sr * 128 + ((sc * 16) ^ wswz))        = kr0;
    *(s16x8*)(KsB + (sr + 32) * 128 + ((sc * 16) ^ wswz)) = kr1;
    *(s16x8*)(VsB + sr * 128 + ((sc * 16) ^ wswz))        = vr0;
    *(s16x8*)(VsB + (sr + 32) * 128 + ((sc * 16) ^ wswz)) = vr1;
    __syncthreads();

    {
      int kvn = (kt + 1 < ntile) ? (kt + 1) * 64 : 0;
      kr0 = *(const s16x8*)(Kh + (size_t)(kvn + sr) * HD_ + sc * 8);
      kr1 = *(const s16x8*)(Kh + (size_t)(kvn + sr + 32) * HD_ + sc * 8);
      vr0 = *(const s16x8*)(Vh + (size_t)sr * T_ + kvn + sc * 8);
      vr1 = *(const s16x8*)(Vh + (size_t)(sr + 32) * T_ + kvn + sc * 8);
    }

    if (kvb > qw + 31) continue;

    f32x16 s0 = {}, s1 = {};
    __builtin_amdgcn_s_setprio(1);
#pragma unroll
    for (int kst = 0; kst < 4; ++kst) {
      s16x8 kb0 = *(const s16x8*)(KsB +
          (((l31) * 128 + kst * 32 + half * 16) ^ rswz));
      s0 = __builtin_amdgcn_mfma_f32_32x32x16_bf16(kb0, qa[kst], s0, 0, 0, 0);
      s16x8 kb1 = *(const s16x8*)(KsB +
          (((32 + l31) * 128 + kst * 32 + half * 16) ^ rswz));
      s1 = __builtin_amdgcn_mfma_f32_32x32x16_bf16(kb1, qa[kst], s1, 0, 0, 0);
    }
    __builtin_amdgcn_s_setprio(0);

    if (kvb + 63 > qw) {
#pragma unroll
      for (int r = 0; r < 16; ++r) {
        int kv0 = kvb + (r & 3) + 8 * (r >> 2) + 4 * half;
        if (kv0 > qrow) s0[r] = -1e30f;
        if (kv0 + 32 > qrow) s1[r] = -1e30f;
      }
    }

    float a0 = fmaxf(fmaxf(s0[0], s0[1]), fmaxf(s0[2], s0[3]));
    float a1 = fmaxf(fmaxf(s0[4], s0[5]), fmaxf(s0[6], s0[7]));
    float a2 = fmaxf(fmaxf(s0[8], s0[9]), fmaxf(s0[10], s0[11]));
    float a3 = fmaxf(fmaxf(s0[12], s0[13]), fmaxf(s0[14], s0[15]));
    float a4 = fmaxf(fmaxf(s1[0], s1[1]), fmaxf(s1[2], s1[3]));
    float a5 = fmaxf(fmaxf(s1[4], s1[5]), fmaxf(s1[6], s1[7]));
    float a6 = fmaxf(fmaxf(s1[8], s1[9]), fmaxf(s1[10], s1[11]));
    float a7 = fmaxf(fmaxf(s1[12], s1[13]), fmaxf(s1[14], s1[15]));
    float mx = fmaxf(fmaxf(fmaxf(a0, a1), fmaxf(a2, a3)),
                     fmaxf(fmaxf(a4, a5), fmaxf(a6, a7)));
    mx = fmaxf(mx, __shfl_xor(mx, 32, 64));

    if (!__all(mx <= m + 8.0f)) {
      float mn = fmaxf(m, mx);
      float alpha = __builtin_amdgcn_exp2f(m - mn);
      m = mn;
      l *= alpha;
#pragma unroll
      for (int i = 0; i < 16; ++i) { oacc[0][i] *= alpha; oacc[1][i] *= alpha; }
    }

    float rs = 0.f;
#pragma unroll
    for (int r = 0; r < 16; ++r) {
      float p0 = __builtin_amdgcn_exp2f(s0[r] - m);
      float p1 = __builtin_amdgcn_exp2f(s1[r] - m);
      s0[r] = p0; s1[r] = p1;
      rs += p0 + p1;
    }
    rs += __shfl_xor(rs, 32, 64);
    l += rs;

    s16x8 pb[4];
#pragma unroll
    for (int ks4 = 0; ks4 < 4; ++ks4) {
      const f32x16& sv = (ks4 < 2) ? s0 : s1;
      const int R = (ks4 & 1) * 8;
      uint32_t A0 = cvtpk(sv[R + 0], sv[R + 1]);
      uint32_t A1 = cvtpk(sv[R + 2], sv[R + 3]);
      uint32_t B0 = cvtpk(sv[R + 4], sv[R + 5]);
      uint32_t B1 = cvtpk(sv[R + 6], sv[R + 7]);
      uint32_t r0 = (uint32_t)__shfl_xor((int)(half ? A0 : B0), 32, 64);
      uint32_t r1 = (uint32_t)__shfl_xor((int)(half ? A1 : B1), 32, 64);
      union { uint32_t u[4]; s16x8 v; } pk_;
      pk_.u[0] = half ? r0 : A0;
      pk_.u[1] = half ? r1 : A1;
      pk_.u[2] = half ? B0 : r0;
      pk_.u[3] = half ? B1 : r1;
      pb[ks4] = pk_.v;
    }

    __builtin_amdgcn_s_setprio(1);
#pragma unroll
    for (int hb = 0; hb < 2; ++hb)
#pragma unroll
      for (int ks4 = 0; ks4 < 4; ++ks4) {
        s16x8 va = *(const s16x8*)(VsB +
            (((hb * 32 + l31) * 128 + ks4 * 32 + half * 16) ^ rswz));
        oacc[hb] = __builtin_amdgcn_mfma_f32_32x32x16_bf16(va, pb[ks4],
                                                           oacc[hb], 0, 0, 0);
      }
    __builtin_amdgcn_s_setprio(0);
  }

  int b = bh >> 4, h = bh & 15;
  float inv = 1.0f / l;
  u16* yrow = Y + ((size_t)b * T_ + qrow) * C_ + h * 64;
#pragma unroll
  for (int hb = 0; hb < 2; ++hb)
#pragma unroll
    for (int rg = 0; rg < 4; ++rg) {
      union { uint32_t u[2]; s16x4 v; } o;
      o.u[0] = cvtpk(oacc[hb][rg * 4 + 0] * inv, oacc[hb][rg * 4 + 1] * inv);
      o.u[1] = cvtpk(oacc[hb][rg * 4 + 2] * inv, oacc[hb][rg * 4 + 3] * inv);
      *(s16x4*)(yrow + hb * 32 + rg * 8 + half * 4) = o.v;
    }
}

// ----------------------------- launcher --------------------------------
extern "C" void kernel_launch(void* const* d_in, const int* in_sizes, int n_in,
                              void* d_out, int out_size, void* d_ws, size_t ws_size,
                              hipStream_t stream) {
  const float* x      = (const float*)d_in[0];
  const float* w_attn = (const float*)d_in[1];
  const float* b_attn = (const float*)d_in[2];
  const float* w_proj = (const float*)d_in[3];
  const float* b_proj = (const float*)d_in[4];
  float* out = (float*)d_out;

  u16* ws  = (u16*)d_ws;
  u16* ya  = ws;                           // [8192][1024] bf16 (attn output)
  u16* wat = ya  + (size_t)M_ * C_;        // [3072][1024] bf16 (W_attn^T)
  u16* wpt = wat + (size_t)N3_ * C_;       // [1024][1024] bf16 (W_proj^T)
  u16* q   = wpt + (size_t)C_ * C_;        // [B,H,T,64] bf16 (pre-scaled)
  u16* k   = q   + (size_t)M_ * C_;        // [B,H,T,64] bf16
  u16* v   = k   + (size_t)M_ * C_;        // [B,H,64,T] bf16 (TRANSPOSED)

  cvt_transpose<<<dim3(N3_ / 64, C_ / 64), dim3(256), 0, stream>>>(w_attn, wat, C_, N3_);
  cvt_transpose<<<dim3(C_ / 64, C_ / 64), dim3(256), 0, stream>>>(w_proj, wpt, C_, C_);

  // QKV GEMM reads x (fp32) directly — conversion fused into A-staging
  gemm_bt<1, 1><<<dim3((M_ / 128) * (N3_ / 128)), dim3(256), 0, stream>>>(
      x, wat, b_attn, nullptr, q, k, v, M_, N3_, C_);

  attn_fwd<<<dim3(64 * 16), dim3(256), 0, stream>>>(q, k, v, ya);

  gemm_bt<0, 0><<<dim3((M_ / 128) * (C_ / 128)), dim3(256), 0, stream>>>(
      ya, wpt, b_proj, out, nullptr, nullptr, nullptr, M_, C_, C_);
}